// Round 1
// baseline (651.913 us; speedup 1.0000x reference)
//
#include <hip/hip_runtime.h>
#include <hip/hip_bf16.h>

#define B_ 32
#define T_ 4096
#define H_ 512
#define NEGV (-1000000000.0f)

using bf16x8  = __attribute__((ext_vector_type(8))) __bf16;
using short8  = __attribute__((ext_vector_type(8))) short;
using short4v = __attribute__((ext_vector_type(4))) short;
using f32x4   = __attribute__((ext_vector_type(4))) float;

static __device__ __forceinline__ short f2bf(float f) {
    // round-to-nearest-even fp32 -> bf16 bits
    unsigned u = __builtin_bit_cast(unsigned, f);
    unsigned r = (u + 0x7fffu + ((u >> 16) & 1u)) >> 16;
    return (short)r;
}

static __device__ __forceinline__ float tanh_fast(float x) {
    // tanh(x) = 1 - 2/(exp(2x)+1); exp via v_exp_f32 (exp2)
    float e = __builtin_amdgcn_exp2f(x * 2.8853900817779268f); // 2*log2(e)
    return 1.0f - 2.0f * __builtin_amdgcn_rcpf(e + 1.0f);
}

static __device__ __forceinline__ f32x4 mfma16(short8 a, short8 b, f32x4 c) {
    return __builtin_amdgcn_mfma_f32_16x16x32_bf16(
        __builtin_bit_cast(bf16x8, a), __builtin_bit_cast(bf16x8, b), c, 0, 0, 0);
}

// ---------------------------------------------------------------------------
// Kernel 1: s[b,o] = sum_k dec[b,k] * Ws[o,k]    (tiny)
// grid (2, B), block 256
__global__ __launch_bounds__(256) void s_kernel(const float* __restrict__ dec,
                                                const float* __restrict__ Ws,
                                                float* __restrict__ s_out) {
    __shared__ float dec_l[H_];
    int b = blockIdx.y;
    int tid = threadIdx.x;
    dec_l[tid]       = dec[b * H_ + tid];
    dec_l[tid + 256] = dec[b * H_ + tid + 256];
    __syncthreads();
    int o = blockIdx.x * 256 + tid;
    const float4* w = (const float4*)(Ws + (size_t)o * H_);
    float acc = 0.f;
#pragma unroll 8
    for (int k = 0; k < H_ / 4; ++k) {
        float4 wv = w[k];
        acc += wv.x * dec_l[4 * k] + wv.y * dec_l[4 * k + 1] +
               wv.z * dec_l[4 * k + 2] + wv.w * dec_l[4 * k + 3];
    }
    s_out[b * H_ + o] = acc;
}

// ---------------------------------------------------------------------------
// Kernel 2: e[b,t] = v . tanh(enc[b,t,:] @ Wh^T + s[b,:]), masked.
// Fused MFMA GEMM (M=B*T, N=512, K=512) with A-frags resident in VGPRs.
// grid (B*T/128), block 256 (4 waves; each wave owns 32 rows).
__global__ __launch_bounds__(256) void e_kernel(const float* __restrict__ enc,
                                                const int* __restrict__ mask,
                                                const float* __restrict__ Wh,
                                                const float* __restrict__ s_in,
                                                const float* __restrict__ v,
                                                float* __restrict__ e_out) {
    constexpr int BSTR = 520;  // shorts per LDS B-row: 512 + 8 pad (16B) -> uniform banks
    __shared__ short lds_b[16 * BSTR];
    __shared__ float s_l[H_];
    __shared__ float v_l[H_];

    const int tid  = threadIdx.x;
    const int wave = tid >> 6;
    const int lane = tid & 63;
    const int q    = lane >> 4;   // quad 0..3
    const int lq   = lane & 15;

    const int row0 = blockIdx.x * 128;  // 128 rows per wg, all same b (4096%128==0)
    const int b    = row0 / T_;

    for (int i = tid; i < H_; i += 256) {
        s_l[i] = s_in[b * H_ + i];
        v_l[i] = v[i];
    }

    // Load this wave's A rows (32 rows x 512 K) as bf16 fragments in registers.
    short8 afrag[2][16];
#pragma unroll
    for (int g = 0; g < 2; ++g) {
        int m = row0 + wave * 32 + g * 16 + lq;
        const float* ap = enc + (size_t)m * H_ + q * 8;
#pragma unroll
        for (int ks = 0; ks < 16; ++ks) {
            float4 f0 = *(const float4*)(ap + ks * 32);
            float4 f1 = *(const float4*)(ap + ks * 32 + 4);
            short8 t;
            t[0] = f2bf(f0.x); t[1] = f2bf(f0.y); t[2] = f2bf(f0.z); t[3] = f2bf(f0.w);
            t[4] = f2bf(f1.x); t[5] = f2bf(f1.y); t[6] = f2bf(f1.z); t[7] = f2bf(f1.w);
            afrag[g][ks] = t;
        }
    }

    float e_acc[2][4] = {};
    __syncthreads();  // s_l/v_l ready

    for (int nt = 0; nt < 32; ++nt) {
        // Cooperative stage of Wh rows [nt*16, nt*16+16) x 512k, fp32 -> bf16 LDS.
#pragma unroll
        for (int j = 0; j < 8; ++j) {
            int flat = (tid + j * 256) * 4;   // float index into 16x512 chunk
            int r = flat >> 9;
            int k = flat & 511;
            float4 wv = *(const float4*)(Wh + (size_t)(nt * 16 + r) * H_ + k);
            short4v sv;
            sv[0] = f2bf(wv.x); sv[1] = f2bf(wv.y); sv[2] = f2bf(wv.z); sv[3] = f2bf(wv.w);
            *(short4v*)&lds_b[r * BSTR + k] = sv;
        }
        __syncthreads();

        f32x4 acc0 = {0.f, 0.f, 0.f, 0.f};
        f32x4 acc1 = {0.f, 0.f, 0.f, 0.f};
#pragma unroll
        for (int ks = 0; ks < 16; ++ks) {
            short8 bf = *(const short8*)&lds_b[lq * BSTR + ks * 32 + q * 8];
            acc0 = mfma16(afrag[0][ks], bf, acc0);
            acc1 = mfma16(afrag[1][ks], bf, acc1);
        }

        float sv = s_l[nt * 16 + lq];
        float vv = v_l[nt * 16 + lq];
#pragma unroll
        for (int r = 0; r < 4; ++r) {
            float t0 = tanh_fast(acc0[r] + sv) * vv;
            float t1 = tanh_fast(acc1[r] + sv) * vv;
            // reduce over the 16 n-lanes (col = lane&15); butterfly leaves sum in all lanes
            t0 += __shfl_xor(t0, 1, 16);
            t0 += __shfl_xor(t0, 2, 16);
            t0 += __shfl_xor(t0, 4, 16);
            t0 += __shfl_xor(t0, 8, 16);
            t1 += __shfl_xor(t1, 1, 16);
            t1 += __shfl_xor(t1, 2, 16);
            t1 += __shfl_xor(t1, 4, 16);
            t1 += __shfl_xor(t1, 8, 16);
            e_acc[0][r] += t0;
            e_acc[1][r] += t1;
        }
        __syncthreads();  // protect lds_b before next stage
    }

    if (lq == 0) {
#pragma unroll
        for (int g = 0; g < 2; ++g)
#pragma unroll
            for (int r = 0; r < 4; ++r) {
                int m = row0 + wave * 32 + g * 16 + q * 4 + r;  // C/D row = quad*4+reg
                e_out[m] = mask[m] ? e_acc[g][r] : NEGV;
            }
    }
}

// ---------------------------------------------------------------------------
// Kernel 3: in-place softmax over T per batch. grid (B), block 256.
__global__ __launch_bounds__(256) void softmax_kernel(float* __restrict__ e) {
    __shared__ float red[256];
    int b = blockIdx.x, tid = threadIdx.x;
    float* eb = e + (size_t)b * T_;
    float m = -3.4e38f;
    for (int i = tid; i < T_; i += 256) m = fmaxf(m, eb[i]);
    red[tid] = m;
    __syncthreads();
    for (int s = 128; s > 0; s >>= 1) {
        if (tid < s) red[tid] = fmaxf(red[tid], red[tid + s]);
        __syncthreads();
    }
    m = red[0];
    __syncthreads();
    float sum = 0.f;
    for (int i = tid; i < T_; i += 256) {
        float p = __builtin_amdgcn_exp2f((eb[i] - m) * 1.4426950408889634f);
        eb[i] = p;
        sum += p;
    }
    red[tid] = sum;
    __syncthreads();
    for (int s = 128; s > 0; s >>= 1) {
        if (tid < s) red[tid] += red[tid + s];
        __syncthreads();
    }
    float inv = 1.0f / red[0];
    for (int i = tid; i < T_; i += 256) eb[i] *= inv;
}

// ---------------------------------------------------------------------------
// Kernel 4: ctx[b,h] = sum_t a[b,t] * enc[b,t,h].  grid (T/256, B), block 256.
__global__ __launch_bounds__(256) void ctx_kernel(const float* __restrict__ enc,
                                                  const float* __restrict__ a,
                                                  float* __restrict__ out) {
    constexpr int TC = 256;
    __shared__ float a_l[TC];
    int b = blockIdx.y, tc = blockIdx.x;
    int tid = threadIdx.x;
    int t0 = tc * TC;
    a_l[tid] = a[(size_t)b * T_ + t0 + tid];
    __syncthreads();
    const float2* ep = (const float2*)(enc + ((size_t)b * T_ + t0) * H_) + tid;
    float2 acc = {0.f, 0.f};
#pragma unroll 4
    for (int t = 0; t < TC; ++t) {
        float2 v2 = ep[(size_t)t * (H_ / 2)];
        float w = a_l[t];
        acc.x += w * v2.x;
        acc.y += w * v2.y;
    }
    atomicAdd(&out[b * H_ + 2 * tid], acc.x);
    atomicAdd(&out[b * H_ + 2 * tid + 1], acc.y);
}

// ---------------------------------------------------------------------------
extern "C" void kernel_launch(void* const* d_in, const int* in_sizes, int n_in,
                              void* d_out, int out_size, void* d_ws, size_t ws_size,
                              hipStream_t stream) {
    (void)in_sizes; (void)n_in; (void)ws_size;
    const float* enc  = (const float*)d_in[0];
    const int*   mask = (const int*)d_in[1];
    const float* dec  = (const float*)d_in[2];
    const float* Wh   = (const float*)d_in[3];
    const float* Ws   = (const float*)d_in[4];
    const float* v    = (const float*)d_in[5];
    float* out = (float*)d_out;

    float* s_buf = (float*)d_ws;           // B*H floats
    float* e_buf = s_buf + B_ * H_;        // B*T floats

    s_kernel<<<dim3(2, B_), 256, 0, stream>>>(dec, Ws, s_buf);
    e_kernel<<<dim3(B_ * T_ / 128), 256, 0, stream>>>(enc, mask, Wh, s_buf, v, e_buf);
    softmax_kernel<<<dim3(B_), 256, 0, stream>>>(e_buf);
    hipMemsetAsync(d_out, 0, (size_t)out_size * sizeof(float), stream);
    ctx_kernel<<<dim3(T_ / 256, B_), 256, 0, stream>>>(enc, e_buf, out);
}

// Round 2
// 508.552 us; speedup vs baseline: 1.2819x; 1.2819x over previous
//
#include <hip/hip_runtime.h>
#include <hip/hip_bf16.h>

#define B_ 32
#define T_ 4096
#define H_ 512
#define NEGV (-1000000000.0f)

using bf16x8  = __attribute__((ext_vector_type(8))) __bf16;
using short8  = __attribute__((ext_vector_type(8))) short;
using f32x4   = __attribute__((ext_vector_type(4))) float;

static __device__ __forceinline__ short f2bf(float f) {
    unsigned u = __builtin_bit_cast(unsigned, f);
    unsigned r = (u + 0x7fffu + ((u >> 16) & 1u)) >> 16;
    return (short)r;
}

static __device__ __forceinline__ float tanh_fast(float x) {
    float e = __builtin_amdgcn_exp2f(x * 2.8853900817779268f); // 2*log2(e)
    return 1.0f - 2.0f * __builtin_amdgcn_rcpf(e + 1.0f);
}

static __device__ __forceinline__ f32x4 mfma16(short8 a, short8 b, f32x4 c) {
    return __builtin_amdgcn_mfma_f32_16x16x32_bf16(
        __builtin_bit_cast(bf16x8, a), __builtin_bit_cast(bf16x8, b), c, 0, 0, 0);
}

// async global->LDS, 16B per lane; lds dest = uniform base + lane*16
#define GLOAD_LDS16(g, l)                                                     \
    __builtin_amdgcn_global_load_lds(                                         \
        (const __attribute__((address_space(1))) unsigned*)(g),               \
        (__attribute__((address_space(3))) unsigned*)(l), 16, 0, 0)

// ---------------------------------------------------------------------------
// Kernel 0: Wh fp32 -> bf16, pre-swizzled for e_kernel LDS staging.
// Layout: chunk nc (32 rows of Wh), row r = n&31, 16B-chunk kc (0..63):
//   stored at Whp + nc*16384 + r*512 + ((kc ^ (n&7)))*8   (short units)
// grid 128, block 256 (one thread per (n, kc))
__global__ __launch_bounds__(256) void wh_prep(const float* __restrict__ Wh,
                                               short* __restrict__ Whp) {
    int id = blockIdx.x * 256 + threadIdx.x;   // 32768 total
    int n = id >> 6, kc = id & 63;
    const float4* src = (const float4*)(Wh + (size_t)n * H_ + kc * 8);
    float4 f0 = src[0];
    float4 f1 = src[1];
    short8 t;
    t[0] = f2bf(f0.x); t[1] = f2bf(f0.y); t[2] = f2bf(f0.z); t[3] = f2bf(f0.w);
    t[4] = f2bf(f1.x); t[5] = f2bf(f1.y); t[6] = f2bf(f1.z); t[7] = f2bf(f1.w);
    int nc = n >> 5, r = n & 31;
    *(short8*)(Whp + nc * 16384 + r * 512 + ((kc ^ (n & 7)) << 3)) = t;
}

// ---------------------------------------------------------------------------
// Kernel 1: s[b,o] = sum_k dec[b,k] * Ws[o,k]    (tiny)
__global__ __launch_bounds__(256) void s_kernel(const float* __restrict__ dec,
                                                const float* __restrict__ Ws,
                                                float* __restrict__ s_out) {
    __shared__ float dec_l[H_];
    int b = blockIdx.y;
    int tid = threadIdx.x;
    dec_l[tid]       = dec[b * H_ + tid];
    dec_l[tid + 256] = dec[b * H_ + tid + 256];
    __syncthreads();
    int o = blockIdx.x * 256 + tid;
    const float4* w = (const float4*)(Ws + (size_t)o * H_);
    float acc = 0.f;
#pragma unroll 8
    for (int k = 0; k < H_ / 4; ++k) {
        float4 wv = w[k];
        acc += wv.x * dec_l[4 * k] + wv.y * dec_l[4 * k + 1] +
               wv.z * dec_l[4 * k + 2] + wv.w * dec_l[4 * k + 3];
    }
    s_out[b * H_ + o] = acc;
}

// ---------------------------------------------------------------------------
// Kernel 2: e[b,t] = v . tanh(enc[b,t,:] @ Wh^T + s[b,:]), masked.
// m97-style: double-buffered LDS N-chunks (32 rows of Wh), global_load_lds
// staging of pre-swizzled bf16 Wh, A-fragments resident in VGPRs,
// single barrier per chunk, e-reduction deferred to one final butterfly.
// grid (B*T/128), block 256 (4 waves x 32 rows).
__global__ __launch_bounds__(256, 2) void e_kernel(const float* __restrict__ enc,
                                                   const int* __restrict__ mask,
                                                   const short* __restrict__ Whp,
                                                   const float* __restrict__ s_in,
                                                   const float* __restrict__ v,
                                                   float* __restrict__ e_out) {
    __shared__ short lds_b[2][32 * 512];   // 2 x 32 KiB
    __shared__ float s_l[H_];
    __shared__ float v_l[H_];

    const int tid  = threadIdx.x;
    const int wave = tid >> 6;
    const int lane = tid & 63;
    const int q    = lane >> 4;   // quad 0..3
    const int lq   = lane & 15;
    const int key  = lq & 7;      // swizzle key (row&7 with 16/32-row chunks)

    const int row0 = blockIdx.x * 128;
    const int b    = row0 / T_;

    for (int i = tid; i < H_; i += 256) {
        s_l[i] = s_in[b * H_ + i];
        v_l[i] = v[i];
    }

    // A rows (32 per wave x 512 K) as bf16 fragments in registers.
    short8 afrag[2][16];
#pragma unroll
    for (int g = 0; g < 2; ++g) {
        int m = row0 + wave * 32 + g * 16 + lq;
        const float* ap = enc + (size_t)m * H_ + q * 8;
#pragma unroll
        for (int ks = 0; ks < 16; ++ks) {
            float4 f0 = *(const float4*)(ap + ks * 32);
            float4 f1 = *(const float4*)(ap + ks * 32 + 4);
            short8 t;
            t[0] = f2bf(f0.x); t[1] = f2bf(f0.y); t[2] = f2bf(f0.z); t[3] = f2bf(f0.w);
            t[4] = f2bf(f1.x); t[5] = f2bf(f1.y); t[6] = f2bf(f1.z); t[7] = f2bf(f1.w);
            afrag[g][ks] = t;
        }
    }

    // Prefetch chunk 0 (32 KiB): per wave 8 x 1KiB global_load_lds.
    {
        const char* gsrc = (const char*)Whp;
#pragma unroll
        for (int j = 0; j < 8; ++j) {
            int off = wave * 8192 + j * 1024;
            GLOAD_LDS16(gsrc + off + lane * 16, (char*)lds_b[0] + off);
        }
    }

    float e_acc[2][4] = {};
    __syncthreads();   // chunk 0 + s_l/v_l ready

    for (int nt = 0; nt < 16; ++nt) {
        if (nt < 15) {
            const char* gsrc = (const char*)Whp + (nt + 1) * 32768;
            short* dst = lds_b[(nt + 1) & 1];
#pragma unroll
            for (int j = 0; j < 8; ++j) {
                int off = wave * 8192 + j * 1024;
                GLOAD_LDS16(gsrc + off + lane * 16, (char*)dst + off);
            }
        }
        const short* cur = lds_b[nt & 1];
#pragma unroll
        for (int s = 0; s < 2; ++s) {
            const short* rowp = cur + (s * 16 + lq) * 512;
            f32x4 acc0 = {0.f, 0.f, 0.f, 0.f};
            f32x4 acc1 = {0.f, 0.f, 0.f, 0.f};
#pragma unroll
            for (int ks = 0; ks < 16; ++ks) {
                short8 bf = *(const short8*)(rowp + (((ks * 4 + q) ^ key) << 3));
                acc0 = mfma16(afrag[0][ks], bf, acc0);
                acc1 = mfma16(afrag[1][ks], bf, acc1);
            }
            int n = nt * 32 + s * 16 + lq;
            float sv = s_l[n];
            float vv = v_l[n];
#pragma unroll
            for (int r = 0; r < 4; ++r) {
                e_acc[0][r] += tanh_fast(acc0[r] + sv) * vv;
                e_acc[1][r] += tanh_fast(acc1[r] + sv) * vv;
            }
        }
        __syncthreads();   // all waves done with cur; prefetch of next complete
    }

    // Final reduction over the 16 n-lanes, then masked store.
#pragma unroll
    for (int g = 0; g < 2; ++g)
#pragma unroll
        for (int r = 0; r < 4; ++r) {
            float t = e_acc[g][r];
            t += __shfl_xor(t, 1, 16);
            t += __shfl_xor(t, 2, 16);
            t += __shfl_xor(t, 4, 16);
            t += __shfl_xor(t, 8, 16);
            if (lq == 0) {
                int m = row0 + wave * 32 + g * 16 + q * 4 + r;
                e_out[m] = mask[m] ? t : NEGV;
            }
        }
}

// ---------------------------------------------------------------------------
// Kernel 3: in-place softmax over T per batch. grid (B), block 256.
__global__ __launch_bounds__(256) void softmax_kernel(float* __restrict__ e) {
    __shared__ float red[256];
    int b = blockIdx.x, tid = threadIdx.x;
    float* eb = e + (size_t)b * T_;
    float m = -3.4e38f;
    for (int i = tid; i < T_; i += 256) m = fmaxf(m, eb[i]);
    red[tid] = m;
    __syncthreads();
    for (int s = 128; s > 0; s >>= 1) {
        if (tid < s) red[tid] = fmaxf(red[tid], red[tid + s]);
        __syncthreads();
    }
    m = red[0];
    __syncthreads();
    float sum = 0.f;
    for (int i = tid; i < T_; i += 256) {
        float p = __builtin_amdgcn_exp2f((eb[i] - m) * 1.4426950408889634f);
        eb[i] = p;
        sum += p;
    }
    red[tid] = sum;
    __syncthreads();
    for (int s = 128; s > 0; s >>= 1) {
        if (tid < s) red[tid] += red[tid + s];
        __syncthreads();
    }
    float inv = 1.0f / red[0];
    for (int i = tid; i < T_; i += 256) eb[i] *= inv;
}

// ---------------------------------------------------------------------------
// Kernel 4: ctx[b,h] = sum_t a[b,t] * enc[b,t,h].  grid (T/128, B), block 256.
__global__ __launch_bounds__(256) void ctx_kernel(const float* __restrict__ enc,
                                                  const float* __restrict__ a,
                                                  float* __restrict__ out) {
    constexpr int TC = 128;
    __shared__ float a_l[TC];
    int b = blockIdx.y, tc = blockIdx.x;
    int tid = threadIdx.x;
    int t0 = tc * TC;
    if (tid < TC) a_l[tid] = a[(size_t)b * T_ + t0 + tid];
    __syncthreads();
    const float2* ep = (const float2*)(enc + ((size_t)b * T_ + t0) * H_) + tid;
    float2 acc = {0.f, 0.f};
#pragma unroll 8
    for (int t = 0; t < TC; ++t) {
        float2 v2 = ep[(size_t)t * (H_ / 2)];
        float w = a_l[t];
        acc.x += w * v2.x;
        acc.y += w * v2.y;
    }
    atomicAdd(&out[b * H_ + 2 * tid], acc.x);
    atomicAdd(&out[b * H_ + 2 * tid + 1], acc.y);
}

// ---------------------------------------------------------------------------
extern "C" void kernel_launch(void* const* d_in, const int* in_sizes, int n_in,
                              void* d_out, int out_size, void* d_ws, size_t ws_size,
                              hipStream_t stream) {
    (void)in_sizes; (void)n_in; (void)ws_size;
    const float* enc  = (const float*)d_in[0];
    const int*   mask = (const int*)d_in[1];
    const float* dec  = (const float*)d_in[2];
    const float* Wh   = (const float*)d_in[3];
    const float* Ws   = (const float*)d_in[4];
    const float* v    = (const float*)d_in[5];
    float* out = (float*)d_out;

    short* whp_buf = (short*)d_ws;                       // 512 KiB
    float* s_buf   = (float*)(whp_buf + 512 * 512);      // 64 KiB
    float* e_buf   = s_buf + B_ * H_;                    // 512 KiB

    wh_prep<<<dim3(128), 256, 0, stream>>>(Wh, whp_buf);
    s_kernel<<<dim3(2, B_), 256, 0, stream>>>(dec, Ws, s_buf);
    e_kernel<<<dim3(B_ * T_ / 128), 256, 0, stream>>>(enc, mask, whp_buf, s_buf, v, e_buf);
    softmax_kernel<<<dim3(B_), 256, 0, stream>>>(e_buf);
    hipMemsetAsync(d_out, 0, (size_t)out_size * sizeof(float), stream);
    ctx_kernel<<<dim3(T_ / 128, B_), 256, 0, stream>>>(enc, e_buf, out);
}